// Round 9
// baseline (538.301 us; speedup 1.0000x reference)
//
#include <hip/hip_runtime.h>
#include <hip/hip_bf16.h>
#include <math.h>

// Problem constants (fixed by reference module)
#define NB   8
#define NPT  4096
#define NQ1  2048   // queries from points1 (via ridx1)
#define NQ2  2048   // queries from points2 (via ridx2)
#define KTOT 64     // 16 (p1) + 16 (p2) + 32 (pc)
#define TILE 1024   // db points staged per stage (4 stages, full db per thread)
#define NTHR 128    // 128 queries per block, each thread scans the FULL db
#define TBUF 24     // candidate buffer slots per lane (trigger at >16, +8 headroom)

// Workspace layout:
//   [0, NB*NPT*KTOT*2)  : unsigned short neighbor indices  (4 MB)
//   [PRM_OFF, +25*4)    : params  A[16] (0.125*Wq Wk^T), u[4], vp[4], c
#define PRM_OFF (4u << 20)

// ---------------------------------------------------------------------------
// Setup: fold attention weights into 4x4 form. logits = f_i A f_j^T + f_i.u + vp.f_j + c
// (row-constant terms are softmax-invariant -> attn kernel uses A, vp only)
__global__ void pf2_setup(const float* __restrict__ Wq, const float* __restrict__ Wk,
                          const float* __restrict__ bq, const float* __restrict__ bk,
                          float* __restrict__ prm) {
    int t = threadIdx.x;
    const float sc = 0.125f; // 1/sqrt(64)
    if (t < 16) {
        int p = t >> 2, q = t & 3;
        float a = 0.f;
        for (int c = 0; c < 64; ++c) a += Wq[p * 64 + c] * Wk[q * 64 + c];
        prm[t] = a * sc;
    } else if (t < 20) {
        int p = t - 16; float a = 0.f;
        for (int c = 0; c < 64; ++c) a += Wq[p * 64 + c] * bk[c];
        prm[t] = a * sc;
    } else if (t < 24) {
        int q = t - 20; float a = 0.f;
        for (int c = 0; c < 64; ++c) a += Wk[q * 64 + c] * bq[c];
        prm[t] = a * sc;
    } else if (t == 24) {
        float a = 0.f;
        for (int c = 0; c < 64; ++c) a += bq[c] * bk[c];
        prm[t] = a * sc;
    }
}

// ---------------------------------------------------------------------------
// Sorted insert (ascending) into register lists via unrolled cndmask chain.
// (R3's exact form — empirically the best measured variant.)
template <int K>
__device__ __forceinline__ void insert_sorted(float (&dl)[K], int (&il)[K], float d, int id) {
#pragma unroll
    for (int j = 0; j < K; ++j) {
        bool sw = d < dl[j];
        float td = dl[j]; int ti = il[j];
        dl[j] = sw ? d : td;
        il[j] = sw ? id : ti;
        d  = sw ? td : d;
        id = sw ? ti : id;
    }
}

// ---------------------------------------------------------------------------
// FULL-db top-K scan: one thread owns one (query, db) pair and scans all 4096
// candidates in index order. vs the split version this pays the K-fill and
// threshold-descent ONCE per query-db (not twice) and needs no cross-half
// merge. Insert order = index order => tie behavior identical to jax top_k.
// Candidates below the lazily-updated threshold are buffered as
// (f32 dist bits, u32 global idx); flush drains them through the register
// top-K with an __any() scalar guard so all-inactive sweeps skip the chain.
template <int K>
__device__ void knn_full(const float* __restrict__ dbp,
                         float qx, float qy, float qz, int tid,
                         float4* __restrict__ tileLds,          // [TILE]
                         uint2* __restrict__ bufLds,            // [TBUF][NTHR]
                         unsigned short* __restrict__ outIdx) {
    float dl[K]; int il[K];
#pragma unroll
    for (int j = 0; j < K; ++j) { dl[j] = INFINITY; il[j] = 0; }
    float thresh = INFINITY;
    int cnt = 0;

    auto flush = [&]() {
        for (int u = 0; u < TBUF; ++u) {
            if (!__any(u < cnt)) break;
            uint2 e = bufLds[u * NTHR + tid];          // always in-bounds
            float s = __uint_as_float(e.x);
            bool pass = (u < cnt) && (s < dl[K - 1]);
            if (__any(pass)) {
                if (pass) insert_sorted<K>(dl, il, s, (int)e.y);
            }
        }
        cnt = 0;
        thresh = dl[K - 1];
    };

    for (int st = 0; st < NPT / TILE; ++st) {
        int base = st * TILE;
        __syncthreads();   // all waves done scanning previous tile
        for (int r = 0; r < TILE / NTHR; ++r) {
            int j = tid + r * NTHR;
            float x = dbp[base + j];
            float y = dbp[NPT + base + j];
            float z = dbp[2 * NPT + base + j];
            tileLds[j] = make_float4(-2.f * x, -2.f * y, -2.f * z,
                                     fmaf(x, x, fmaf(y, y, z * z)));
        }
        __syncthreads();

        for (int c0 = 0; c0 < TILE; c0 += 8) {
            float sv[8];
#pragma unroll
            for (int u = 0; u < 8; ++u) {
                float4 p = tileLds[c0 + u];   // wave-uniform -> LDS broadcast
                sv[u] = fmaf(p.x, qx, fmaf(p.y, qy, fmaf(p.z, qz, p.w)));
            }
#pragma unroll
            for (int u = 0; u < 8; ++u) {
                if (sv[u] < thresh) {
                    bufLds[cnt * NTHR + tid] =
                        make_uint2(__float_as_uint(sv[u]), (unsigned)(base + c0 + u));
                    ++cnt;
                }
            }
            if (__any(cnt > TBUF - 8)) flush();   // headroom guard (max +8/batch)
        }
    }
    flush();   // final drain

    unsigned* o32 = (unsigned*)outIdx;   // 4B-aligned (segment offsets even)
#pragma unroll
    for (int u = 0; u < K / 2; ++u)
        o32[u] = (unsigned)(unsigned short)il[2 * u] |
                 ((unsigned)(unsigned short)il[2 * u + 1] << 16);
}

// grid = NB * 3 * (NPT/NTHR) blocks; block: 128 queries x 1 db (full scan).
// Heavy (K=32, pc) blocks dispatched FIRST so the ramp-down tail is light
// (R7's verified tail-shaping win).
__global__ __launch_bounds__(NTHR) void pf2_knn(const float* __restrict__ p1,
                                                const float* __restrict__ p2,
                                                const float* __restrict__ pc,
                                                const int* __restrict__ ridx1,
                                                const int* __restrict__ ridx2,
                                                unsigned short* __restrict__ wsIdx) {
    __shared__ float4 tileLds[TILE];                 // 16 KB
    __shared__ uint2  bufLds[TBUF * NTHR];           // 24 KB

    int bid = blockIdx.x;
    int dbslot = bid >> 8;                     // 0..2 (outermost)
    int db = (dbslot == 0) ? 2 : dbslot - 1;   // dispatch order: pc, p1, p2
    int rem = bid & 255;
    int b = rem >> 5;
    int chunk = rem & 31;
    int tid = threadIdx.x;
    int i = chunk * NTHR + tid;

    int j0; const float* srcp;
    if (i < NQ1) { j0 = ridx1[b * NQ1 + i]; srcp = p1; }
    else         { j0 = ridx2[b * NQ2 + (i - NQ1)]; srcp = p2; }
    const float* sb = srcp + (size_t)b * 3 * NPT;
    float qx = sb[j0], qy = sb[NPT + j0], qz = sb[2 * NPT + j0];

    const float* dbp = (db == 0 ? p1 : db == 1 ? p2 : pc) + (size_t)b * 3 * NPT;
    unsigned short* out = wsIdx + (size_t)(b * NPT + i) * KTOT +
                          (db == 0 ? 0 : db == 1 ? 16 : 32);
    if (db < 2) knn_full<16>(dbp, qx, qy, qz, tid, tileLds, bufLds, out);
    else        knn_full<32>(dbp, qx, qy, qz, tid, tileLds, bufLds, out);
}

// ---------------------------------------------------------------------------
// Attention + fusion. One wave per point group (64 lanes <-> 64 neighbors).
// Rank-4 factorization: logits_ij = f_i.(A f_j) + vp.f_j (+ row-const, dropped);
// y_i = (sum_j e_ij f_j / S_i) Wv + bv ; score = max_ch y ; out = sum_i w_i nn_i.
__global__ __launch_bounds__(256) void pf2_attn(const float* __restrict__ p1,
                                                const float* __restrict__ p2,
                                                const float* __restrict__ pc,
                                                const int* __restrict__ ridx1,
                                                const int* __restrict__ ridx2,
                                                const float* __restrict__ Wv,
                                                const float* __restrict__ bv,
                                                const float* __restrict__ prm,
                                                const unsigned short* __restrict__ wsIdx,
                                                float* __restrict__ out) {
    __shared__ float4 wvt[64];      // Wv columns (transposed)
    __shared__ float  bvs[64];
    __shared__ float  prms[25];
    __shared__ float4 gl[4][64];    // A f_j per wave
    __shared__ float4 fl[4][64];    // f_j per wave
    __shared__ float  sl[4][64];    // vp.f_j per wave

    int tid = threadIdx.x;
    if (tid < 64) {
        wvt[tid] = make_float4(Wv[tid], Wv[64 + tid], Wv[128 + tid], Wv[192 + tid]);
        bvs[tid] = bv[tid];
    } else if (tid < 89) {
        prms[tid - 64] = prm[tid - 64];
    }
    __syncthreads();

    int wv = tid >> 6, lane = tid & 63;
    int g = blockIdx.x * 4 + wv;
    int b = g >> 12;
    int i = g & 4095;

    int j0; const float* srcp;
    if (i < NQ1) { j0 = ridx1[b * NQ1 + i]; srcp = p1; }
    else         { j0 = ridx2[b * NQ2 + (i - NQ1)]; srcp = p2; }
    const float* sb = srcp + (size_t)b * 3 * NPT;
    float qx = sb[j0], qy = sb[NPT + j0], qz = sb[2 * NPT + j0];

    int nidx = (int)wsIdx[(size_t)(b * NPT + i) * KTOT + lane];
    const float* dbp = (lane < 16 ? p1 : lane < 32 ? p2 : pc) + (size_t)b * 3 * NPT;
    float nx = dbp[nidx], ny = dbp[NPT + nidx], nz = dbp[2 * NPT + nidx];
    float fx = nx - qx, fy = ny - qy, fz = nz - qz;
    float sq = fx * fx + fy * fy + fz * fz;
    float fw = sq > 0.f ? sqrtf(sq) : 0.f;   // safe norm, matches reference

    float gx = prms[0]  * fx + prms[1]  * fy + prms[2]  * fz + prms[3]  * fw;
    float gy = prms[4]  * fx + prms[5]  * fy + prms[6]  * fz + prms[7]  * fw;
    float gz = prms[8]  * fx + prms[9]  * fy + prms[10] * fz + prms[11] * fw;
    float gw = prms[12] * fx + prms[13] * fy + prms[14] * fz + prms[15] * fw;
    float sj = prms[20] * fx + prms[21] * fy + prms[22] * fz + prms[23] * fw;

    gl[wv][lane] = make_float4(gx, gy, gz, gw);
    fl[wv][lane] = make_float4(fx, fy, fz, fw);
    sl[wv][lane] = sj;
    __syncthreads();

    // pass 1: row max
    float m = -INFINITY;
    for (int j = 0; j < 64; ++j) {
        float4 gj = gl[wv][j];
        float l = fx * gj.x + fy * gj.y + fz * gj.z + fw * gj.w + sl[wv][j];
        m = fmaxf(m, l);
    }
    // pass 2: exp-sum and H = sum e*f
    float S = 0.f, H0 = 0.f, H1 = 0.f, H2 = 0.f, H3 = 0.f;
    for (int j = 0; j < 64; ++j) {
        float4 gj = gl[wv][j];
        float4 fj = fl[wv][j];
        float l = fx * gj.x + fy * gj.y + fz * gj.z + fw * gj.w + sl[wv][j];
        float e = __expf(l - m);
        S += e;
        H0 += e * fj.x; H1 += e * fj.y; H2 += e * fj.z; H3 += e * fj.w;
    }
    float rS = 1.f / S;

    float smax = -INFINITY;
    for (int ch = 0; ch < 64; ++ch) {
        float4 wc = wvt[ch];
        float t = H0 * wc.x + H1 * wc.y + H2 * wc.z + H3 * wc.w;
        float yv = fmaf(t, rS, bvs[ch]);
        smax = fmaxf(smax, yv);
    }

    float M = smax;
    for (int off = 32; off; off >>= 1) M = fmaxf(M, __shfl_xor(M, off));
    float e = __expf(smax - M);
    float E = e;
    for (int off = 32; off; off >>= 1) E += __shfl_xor(E, off);
    float w = e / E;
    float px = w * nx, py = w * ny, pz = w * nz;
    for (int off = 32; off; off >>= 1) {
        px += __shfl_xor(px, off);
        py += __shfl_xor(py, off);
        pz += __shfl_xor(pz, off);
    }
    if (lane == 0) {
        float* ob = out + (size_t)b * 3 * NPT + i;
        ob[0] = px; ob[NPT] = py; ob[2 * NPT] = pz;
    }
}

// ---------------------------------------------------------------------------
extern "C" void kernel_launch(void* const* d_in, const int* in_sizes, int n_in,
                              void* d_out, int out_size, void* d_ws, size_t ws_size,
                              hipStream_t stream) {
    const float* p1 = (const float*)d_in[0];
    const float* p2 = (const float*)d_in[1];
    const float* pc = (const float*)d_in[2];
    const float* Wq = (const float*)d_in[3];
    const float* Wk = (const float*)d_in[4];
    const float* Wv = (const float*)d_in[5];
    const float* bq = (const float*)d_in[6];
    const float* bk = (const float*)d_in[7];
    const float* bv = (const float*)d_in[8];
    const int* ridx1 = (const int*)d_in[9];
    const int* ridx2 = (const int*)d_in[10];
    float* out = (float*)d_out;

    unsigned short* wsIdx = (unsigned short*)d_ws;
    float* prm = (float*)((char*)d_ws + PRM_OFF);

    pf2_setup<<<1, 32, 0, stream>>>(Wq, Wk, bq, bk, prm);
    pf2_knn<<<NB * 3 * (NPT / NTHR), NTHR, 0, stream>>>(p1, p2, pc, ridx1, ridx2, wsIdx);
    pf2_attn<<<NB * NPT / 4, 256, 0, stream>>>(p1, p2, pc, ridx1, ridx2, Wv, bv, prm, wsIdx, out);
}

// Round 10
// 377.703 us; speedup vs baseline: 1.4252x; 1.4252x over previous
//
#include <hip/hip_runtime.h>
#include <hip/hip_bf16.h>
#include <math.h>

// Problem constants (fixed by reference module)
#define NB   8
#define NPT  4096
#define NQ1  2048   // queries from points1 (via ridx1)
#define NQ2  2048   // queries from points2 (via ridx2)
#define KTOT 64     // 16 (p1) + 16 (p2) + 32 (pc)
#define TILE 1024
#define NTHR 256    // 128 queries x 2 db-halves
#define QPB  128
#define TBUF 16
#define MPAD 33     // padded merge-row stride -> conflict-free (q+j)%32 banks

// Workspace layout:
//   [0, NB*NPT*KTOT*2)  : unsigned short neighbor indices  (4 MB)
//   [PRM_OFF, +25*4)    : params  A[16] (0.125*Wq Wk^T), u[4], vp[4], c
#define PRM_OFF (4u << 20)

// ---------------------------------------------------------------------------
// Setup: fold attention weights into 4x4 form. logits = f_i A f_j^T + f_i.u + vp.f_j + c
// (row-constant terms are softmax-invariant -> attn kernel uses A, vp only)
__global__ void pf2_setup(const float* __restrict__ Wq, const float* __restrict__ Wk,
                          const float* __restrict__ bq, const float* __restrict__ bk,
                          float* __restrict__ prm) {
    int t = threadIdx.x;
    const float sc = 0.125f; // 1/sqrt(64)
    if (t < 16) {
        int p = t >> 2, q = t & 3;
        float a = 0.f;
        for (int c = 0; c < 64; ++c) a += Wq[p * 64 + c] * Wk[q * 64 + c];
        prm[t] = a * sc;
    } else if (t < 20) {
        int p = t - 16; float a = 0.f;
        for (int c = 0; c < 64; ++c) a += Wq[p * 64 + c] * bk[c];
        prm[t] = a * sc;
    } else if (t < 24) {
        int q = t - 20; float a = 0.f;
        for (int c = 0; c < 64; ++c) a += Wk[q * 64 + c] * bq[c];
        prm[t] = a * sc;
    } else if (t == 24) {
        float a = 0.f;
        for (int c = 0; c < 64; ++c) a += bq[c] * bk[c];
        prm[t] = a * sc;
    }
}

// ---------------------------------------------------------------------------
// Branch-free sorted insert (ascending) with NO serial dependency chain:
//   dl'[j] = med3(d, old dl[j-1], old dl[j])   (exact; one v_med3_f32)
//   il'[j] = (d < old dl[j-1]) ? il[j-1] : (d < old dl[j]) ? id : il[j]
// All slots read only OLD state -> full ILP; 4 instrs/slot vs 5-6 serialized.
// Tie rule (d == dl[j] placed after) identical to the cndmask chain and to
// jax top_k arrival order -> identical selection sets.
template <int K>
__device__ __forceinline__ void insert_med3(float (&dl)[K], int (&il)[K], float d, int id) {
    float pd = -INFINITY; int pi = 0;
    bool cp = false;                      // d < old dl[j-1]
#pragma unroll
    for (int j = 0; j < K; ++j) {
        float oj = dl[j]; int ij = il[j];
        bool cj = d < oj;
        dl[j] = __builtin_amdgcn_fmed3f(d, pd, oj);
        il[j] = cp ? pi : (cj ? id : ij);
        pd = oj; pi = ij; cp = cj;
    }
}

// ---------------------------------------------------------------------------
// Half-db top-K scan + cross-half merge (R7 structure, med3 insert).
// Each thread scans 2048 candidates (half h = tid>>7) with register top-K;
// halves merged via LDS. Rank key s = |p|^2 - 2 q.p is rank-identical to
// reference d2. il[] holds GLOBAL indices -> merge adds no offset.
template <int K>
__device__ void knn_half(const float* __restrict__ dbp,
                         float qx, float qy, float qz, int tid,
                         float4* __restrict__ tileLds,          // [2][TILE]
                         unsigned short* __restrict__ bufLds,   // [TBUF][NTHR]
                         float* __restrict__ mD,                // [QPB][MPAD] (aliases tile)
                         unsigned short* __restrict__ mI,       // [QPB][MPAD] (aliases tile)
                         unsigned short* __restrict__ outIdx) {
    const int q = tid & (QPB - 1), h = tid >> 7;
    float dl[K]; int il[K];
#pragma unroll
    for (int j = 0; j < K; ++j) { dl[j] = INFINITY; il[j] = 0; }
    float thresh = INFINITY;
    int cnt = 0;
    float4* tp = tileLds + h * TILE;

    for (int st = 0; st < 2; ++st) {
        int base = h * 2048 + st * TILE;
        __syncthreads();   // prior flush (which reads tile) done before overwrite
        for (int r = 0; r < TILE / QPB; ++r) {
            int j = q + r * QPB;
            float x = dbp[base + j];
            float y = dbp[NPT + base + j];
            float z = dbp[2 * NPT + base + j];
            tp[j] = make_float4(-2.f * x, -2.f * y, -2.f * z,
                                fmaf(x, x, fmaf(y, y, z * z)));
        }
        __syncthreads();

        for (int c0 = 0; c0 < TILE; c0 += 8) {
            float sv[8];
#pragma unroll
            for (int u = 0; u < 8; ++u) {
                float4 p = tp[c0 + u];        // wave-uniform -> LDS broadcast
                sv[u] = fmaf(p.x, qx, fmaf(p.y, qy, fmaf(p.z, qz, p.w)));
            }
#pragma unroll
            for (int u = 0; u < 8; ++u) {
                if (sv[u] < thresh) {
                    bufLds[cnt * NTHR + tid] = (unsigned short)(c0 + u);
                    ++cnt;
                }
            }
            if (__any(cnt > TBUF - 8)) {      // flush: amortized inserts
                for (int u = 0; u < TBUF; ++u) {
                    if (!__any(u < cnt)) break;
                    if (u < cnt) {
                        int j = bufLds[u * NTHR + tid];
                        float4 p = tp[j];
                        float s = fmaf(p.x, qx, fmaf(p.y, qy, fmaf(p.z, qz, p.w)));
                        if (s < dl[K - 1]) insert_med3<K>(dl, il, s, base + j);
                    }
                }
                cnt = 0;
                thresh = dl[K - 1];
            }
        }
        // mandatory end-of-tile flush (buffer indices are tile-local)
        for (int u = 0; u < TBUF; ++u) {
            if (!__any(u < cnt)) break;
            if (u < cnt) {
                int j = bufLds[u * NTHR + tid];
                float4 p = tp[j];
                float s = fmaf(p.x, qx, fmaf(p.y, qy, fmaf(p.z, qz, p.w)));
                if (s < dl[K - 1]) insert_med3<K>(dl, il, s, base + j);
            }
        }
        cnt = 0;
        thresh = dl[K - 1];
    }

    __syncthreads();  // scanning done; tile LDS reused as merge area
    if (h == 1) {
#pragma unroll
        for (int j = 0; j < K; ++j) {
            mD[q * MPAD + j] = dl[j];
            mI[q * MPAD + j] = (unsigned short)il[j];   // global idx, in [2048,4096)
        }
    }
    __syncthreads();
    if (h == 0) {
#pragma unroll
        for (int j = 0; j < K; ++j) {
            float d = mD[q * MPAD + j];
            int id = (int)mI[q * MPAD + j];             // already global — no offset
            if (d < dl[K - 1]) insert_med3<K>(dl, il, d, id);
        }
        unsigned* o32 = (unsigned*)outIdx;   // 4B-aligned (segment offsets even)
#pragma unroll
        for (int u = 0; u < K / 2; ++u)
            o32[u] = (unsigned)(unsigned short)il[2 * u] |
                     ((unsigned)(unsigned short)il[2 * u + 1] << 16);
    }
}

// grid = NB * 3 * (NPT/QPB) blocks; block: 128 queries x 2 db-halves.
// Heavy (K=32, pc) blocks dispatched FIRST so the ramp-down tail is light
// (R7's verified tail-shaping win).
__global__ __launch_bounds__(NTHR) void pf2_knn(const float* __restrict__ p1,
                                                const float* __restrict__ p2,
                                                const float* __restrict__ pc,
                                                const int* __restrict__ ridx1,
                                                const int* __restrict__ ridx2,
                                                unsigned short* __restrict__ wsIdx) {
    __shared__ float4 tileLds[2 * TILE];                 // 32 KB (aliased by merge)
    __shared__ unsigned short bufLds[TBUF * NTHR];       // 8 KB
    float* mD = (float*)tileLds;                         // [QPB][MPAD] floats
    unsigned short* mI = (unsigned short*)(mD + QPB * MPAD);

    int bid = blockIdx.x;
    int dbslot = bid >> 8;                     // 0..2 (outermost)
    int db = (dbslot == 0) ? 2 : dbslot - 1;   // dispatch order: pc, p1, p2
    int rem = bid & 255;
    int b = rem >> 5;
    int chunk = rem & 31;
    int tid = threadIdx.x;
    int i = chunk * QPB + (tid & (QPB - 1));

    int j0; const float* srcp;
    if (i < NQ1) { j0 = ridx1[b * NQ1 + i]; srcp = p1; }
    else         { j0 = ridx2[b * NQ2 + (i - NQ1)]; srcp = p2; }
    const float* sb = srcp + (size_t)b * 3 * NPT;
    float qx = sb[j0], qy = sb[NPT + j0], qz = sb[2 * NPT + j0];

    const float* dbp = (db == 0 ? p1 : db == 1 ? p2 : pc) + (size_t)b * 3 * NPT;
    unsigned short* out = wsIdx + (size_t)(b * NPT + i) * KTOT +
                          (db == 0 ? 0 : db == 1 ? 16 : 32);
    if (db < 2) knn_half<16>(dbp, qx, qy, qz, tid, tileLds, bufLds, mD, mI, out);
    else        knn_half<32>(dbp, qx, qy, qz, tid, tileLds, bufLds, mD, mI, out);
}

// ---------------------------------------------------------------------------
// Attention + fusion. One wave per point group (64 lanes <-> 64 neighbors).
// Rank-4 factorization: logits_ij = f_i.(A f_j) + vp.f_j (+ row-const, dropped);
// y_i = (sum_j e_ij f_j / S_i) Wv + bv ; score = max_ch y ; out = sum_i w_i nn_i.
__global__ __launch_bounds__(256) void pf2_attn(const float* __restrict__ p1,
                                                const float* __restrict__ p2,
                                                const float* __restrict__ pc,
                                                const int* __restrict__ ridx1,
                                                const int* __restrict__ ridx2,
                                                const float* __restrict__ Wv,
                                                const float* __restrict__ bv,
                                                const float* __restrict__ prm,
                                                const unsigned short* __restrict__ wsIdx,
                                                float* __restrict__ out) {
    __shared__ float4 wvt[64];      // Wv columns (transposed)
    __shared__ float  bvs[64];
    __shared__ float  prms[25];
    __shared__ float4 gl[4][64];    // A f_j per wave
    __shared__ float4 fl[4][64];    // f_j per wave
    __shared__ float  sl[4][64];    // vp.f_j per wave

    int tid = threadIdx.x;
    if (tid < 64) {
        wvt[tid] = make_float4(Wv[tid], Wv[64 + tid], Wv[128 + tid], Wv[192 + tid]);
        bvs[tid] = bv[tid];
    } else if (tid < 89) {
        prms[tid - 64] = prm[tid - 64];
    }
    __syncthreads();

    int wv = tid >> 6, lane = tid & 63;
    int g = blockIdx.x * 4 + wv;
    int b = g >> 12;
    int i = g & 4095;

    int j0; const float* srcp;
    if (i < NQ1) { j0 = ridx1[b * NQ1 + i]; srcp = p1; }
    else         { j0 = ridx2[b * NQ2 + (i - NQ1)]; srcp = p2; }
    const float* sb = srcp + (size_t)b * 3 * NPT;
    float qx = sb[j0], qy = sb[NPT + j0], qz = sb[2 * NPT + j0];

    int nidx = (int)wsIdx[(size_t)(b * NPT + i) * KTOT + lane];
    const float* dbp = (lane < 16 ? p1 : lane < 32 ? p2 : pc) + (size_t)b * 3 * NPT;
    float nx = dbp[nidx], ny = dbp[NPT + nidx], nz = dbp[2 * NPT + nidx];
    float fx = nx - qx, fy = ny - qy, fz = nz - qz;
    float sq = fx * fx + fy * fy + fz * fz;
    float fw = sq > 0.f ? sqrtf(sq) : 0.f;   // safe norm, matches reference

    float gx = prms[0]  * fx + prms[1]  * fy + prms[2]  * fz + prms[3]  * fw;
    float gy = prms[4]  * fx + prms[5]  * fy + prms[6]  * fz + prms[7]  * fw;
    float gz = prms[8]  * fx + prms[9]  * fy + prms[10] * fz + prms[11] * fw;
    float gw = prms[12] * fx + prms[13] * fy + prms[14] * fz + prms[15] * fw;
    float sj = prms[20] * fx + prms[21] * fy + prms[22] * fz + prms[23] * fw;

    gl[wv][lane] = make_float4(gx, gy, gz, gw);
    fl[wv][lane] = make_float4(fx, fy, fz, fw);
    sl[wv][lane] = sj;
    __syncthreads();

    // pass 1: row max
    float m = -INFINITY;
    for (int j = 0; j < 64; ++j) {
        float4 gj = gl[wv][j];
        float l = fx * gj.x + fy * gj.y + fz * gj.z + fw * gj.w + sl[wv][j];
        m = fmaxf(m, l);
    }
    // pass 2: exp-sum and H = sum e*f
    float S = 0.f, H0 = 0.f, H1 = 0.f, H2 = 0.f, H3 = 0.f;
    for (int j = 0; j < 64; ++j) {
        float4 gj = gl[wv][j];
        float4 fj = fl[wv][j];
        float l = fx * gj.x + fy * gj.y + fz * gj.z + fw * gj.w + sl[wv][j];
        float e = __expf(l - m);
        S += e;
        H0 += e * fj.x; H1 += e * fj.y; H2 += e * fj.z; H3 += e * fj.w;
    }
    float rS = 1.f / S;

    float smax = -INFINITY;
    for (int ch = 0; ch < 64; ++ch) {
        float4 wc = wvt[ch];
        float t = H0 * wc.x + H1 * wc.y + H2 * wc.z + H3 * wc.w;
        float yv = fmaf(t, rS, bvs[ch]);
        smax = fmaxf(smax, yv);
    }

    float M = smax;
    for (int off = 32; off; off >>= 1) M = fmaxf(M, __shfl_xor(M, off));
    float e = __expf(smax - M);
    float E = e;
    for (int off = 32; off; off >>= 1) E += __shfl_xor(E, off);
    float w = e / E;
    float px = w * nx, py = w * ny, pz = w * nz;
    for (int off = 32; off; off >>= 1) {
        px += __shfl_xor(px, off);
        py += __shfl_xor(py, off);
        pz += __shfl_xor(pz, off);
    }
    if (lane == 0) {
        float* ob = out + (size_t)b * 3 * NPT + i;
        ob[0] = px; ob[NPT] = py; ob[2 * NPT] = pz;
    }
}

// ---------------------------------------------------------------------------
extern "C" void kernel_launch(void* const* d_in, const int* in_sizes, int n_in,
                              void* d_out, int out_size, void* d_ws, size_t ws_size,
                              hipStream_t stream) {
    const float* p1 = (const float*)d_in[0];
    const float* p2 = (const float*)d_in[1];
    const float* pc = (const float*)d_in[2];
    const float* Wq = (const float*)d_in[3];
    const float* Wk = (const float*)d_in[4];
    const float* Wv = (const float*)d_in[5];
    const float* bq = (const float*)d_in[6];
    const float* bk = (const float*)d_in[7];
    const float* bv = (const float*)d_in[8];
    const int* ridx1 = (const int*)d_in[9];
    const int* ridx2 = (const int*)d_in[10];
    float* out = (float*)d_out;

    unsigned short* wsIdx = (unsigned short*)d_ws;
    float* prm = (float*)((char*)d_ws + PRM_OFF);

    pf2_setup<<<1, 32, 0, stream>>>(Wq, Wk, bq, bk, prm);
    pf2_knn<<<NB * 3 * (NPT / QPB), NTHR, 0, stream>>>(p1, p2, pc, ridx1, ridx2, wsIdx);
    pf2_attn<<<NB * NPT / 4, 256, 0, stream>>>(p1, p2, pc, ridx1, ridx2, Wv, bv, prm, wsIdx, out);
}